// Round 5
// baseline (280.648 us; speedup 1.0000x reference)
//
#include <hip/hip_runtime.h>
#include <stdint.h>

// ---------------- problem constants ----------------
#define S_LEN 256
#define OUT1  262      // S + 7 - 1
#define K1SEL 131      // ceil((2-1)/2 * 262)
#define OUT2  135      // 131 + 5 - 1
// ws layout (floats)
#define W1T_OFF 0          // w1t[d][k][f]      64*7*8   = 3584
#define W2T_OFF 3584       // w2t[g][ic][k][f2] 32*8*5*16= 20480
#define B1C_OFF 24064      // b1c[r2][f]        32*8
#define B2C_OFF 24320      // b2c[r3][f2]       16*16
#define WS_FLOATS 24576

__device__ __forceinline__ int lane_prefix(unsigned long long m) {
    return __builtin_amdgcn_mbcnt_hi((uint32_t)(m >> 32),
           __builtin_amdgcn_mbcnt_lo((uint32_t)m, 0));
}
__device__ __forceinline__ uint32_t f2ord(float x) {
    uint32_t b = __float_as_uint(x);
    return (b & 0x80000000u) ? ~b : (b | 0x80000000u);
}
__device__ __forceinline__ float ord2f(uint32_t s) {
    uint32_t b = (s & 0x80000000u) ? (s & 0x7FFFFFFFu) : ~s;
    return __uint_as_float(b);
}
__device__ __forceinline__ float fast_tanh(float x) {
    float e = __expf(2.0f * x);
    return (e - 1.0f) / (e + 1.0f);
}

// ------------- prep: transpose weights / fold biases into ws -------------
extern "C" __global__ void dcnn_prep(const float* __restrict__ w1, const float* __restrict__ b1,
                                     const float* __restrict__ w2, const float* __restrict__ b2,
                                     float* __restrict__ ws) {
    int i = blockIdx.x * 256 + threadIdx.x;   // 96*256 == 24576 == WS_FLOATS
    if (i < W2T_OFF) {                        // w1t[d][k][f] = w1[(d*8+f)*7 + k]
        int d = i / 56, r = i % 56, k = r / 8, f = r % 8;
        ws[i] = w1[(d * 8 + f) * 7 + k];
    } else if (i < B1C_OFF) {                 // w2t[g][ic][k][f2] = w2[((g*16+f2)*8+ic)*5+k]
        int q = i - W2T_OFF;
        int g = q / 640, r = q % 640;
        int ic = r / 80, r2 = r % 80;
        int k = r2 / 16, f2 = r2 % 16;
        ws[i] = w2[((g * 16 + f2) * 8 + ic) * 5 + k];
    } else if (i < B2C_OFF) {                 // b1c[r2][f] = b1[2r2*8+f] + b1[(2r2+1)*8+f]
        int q = i - B1C_OFF;
        int r2 = q / 8, f = q % 8;
        ws[i] = b1[(2 * r2) * 8 + f] + b1[(2 * r2 + 1) * 8 + f];
    } else {                                  // b2c[r3][f2]
        int q = i - B2C_OFF;
        int r3 = q / 16, f2 = q % 16;
        ws[i] = b2[(2 * r3) * 16 + f2] + b2[(2 * r3 + 1) * 16 + f2];
    }
}

// ------------- main: one block (512 thr, 8 waves) per sample, 2 r3-slices/wave -------------
// LDS: per-wave union region (2240 floats = 8960 B):
//   phase A (conv1 input): rows = float4[272], idx t+8, zero guards at 0..7 & 264..271
//   phase B (conv2 input): p1[2][8][140], data at pos+4, zero guards 0..3 & 135..138
// Safe because conv1 fully consumes rows into registers before select writes p1
// (same-wave program order; compiler orders the aliasing LDS ops).
//
// Register budget (R2/R3/R4 evidence): __launch_bounds__(512,N)'s 2nd arg acts
// as min BLOCKS/CU on this toolchain: (512,4) -> 32 waves/CU -> hard 64-VGPR cap
// (observed 64 in R2+R4; R2 spilled 319 MB to meet it). LDS (75.5 KB) only ever
// admits 2 blocks/CU, so the 64-cap buys nothing and forces acc[16][5] into
// AGPR shuffles. Explicit backend attrs request exactly 4 waves/EU (=16
// waves/CU = 2 blocks/CU) -> 128-reg cap, matching the LDS limit.
// CRITICAL (R3 lesson): the select-1 channel loop MUST be fully unrolled; a
// runtime channel index into acc[16][5] forces the whole array to scratch
// (~300 MB of HBM spill traffic measured in R2/R3).
extern "C" __global__
__attribute__((amdgpu_flat_work_group_size(512, 512), amdgpu_waves_per_eu(4, 4)))
void dcnn_main(const int* __restrict__ x, const float* __restrict__ emb,
               const float* __restrict__ fcw, const float* __restrict__ fcb,
               const float* __restrict__ ws, float* __restrict__ out) {
    __shared__ float uni[8][2240];        // 71680 B
    __shared__ int   xs[S_LEN];           // 1 KB
    __shared__ float p2[1024];            // 4 KB : [ (r3*16+f2)*4 + j ]
    __shared__ float fred[8][6];

    const int b    = blockIdx.x;
    const int tid  = threadIdx.x;
    const int lane = tid & 63;
    const int wv   = __builtin_amdgcn_readfirstlane(tid >> 6);

    const float* w1t = ws + W1T_OFF;
    const float* w2t = ws + W2T_OFF;
    const float* b1c = ws + B1C_OFF;
    const float* b2c = ws + B2C_OFF;

    if (tid < S_LEN) xs[tid] = x[b * S_LEN + tid];
    __syncthreads();

    float4* rowsW = (float4*)&uni[wv][0];   // 272 float4 = 1088 floats
    float*  p1w   = &uni[wv][0];            // [ch:16][140], ch = rs*8+f

#pragma unroll 1
    for (int it = 0; it < 2; ++it) {
        const int r3 = wv * 2 + it;

        // ---- guards + stage 4 embedding rows (d = 4r3..4r3+3) as float4 per t ----
        if (lane < 16) rowsW[(lane < 8) ? lane : (256 + lane)] = make_float4(0.f, 0.f, 0.f, 0.f);
#pragma unroll
        for (int m = 0; m < 4; ++m) {
            int t = lane + 64 * m;
            int xi = xs[t];
            float4 v = *(const float4*)(emb + (size_t)xi * 64 + 4 * r3);
            rowsW[8 + t] = v;
        }

        // ---- conv1 (K=7, depthwise) + fold: 16 channels (rs*8+f), t = lane+64m ----
        float acc[16][5];
#pragma unroll
        for (int ch = 0; ch < 16; ++ch) {
            float bz = b1c[(2 * r3 + (ch >> 3)) * 8 + (ch & 7)];
#pragma unroll
            for (int m = 0; m < 5; ++m) acc[ch][m] = bz;
        }
        int tA[5];
#pragma unroll
        for (int m = 0; m < 5; ++m) { int t = lane + 64 * m; tA[m] = (t < OUT1) ? t : (OUT1 - 1); }

#pragma unroll 1
        for (int k = 0; k < 7; ++k) {
            float wa[16], wb[16];
#pragma unroll
            for (int ch = 0; ch < 16; ++ch) {
                int d0 = 4 * r3 + 2 * (ch >> 3);
                wa[ch] = w1t[(d0 * 7 + k) * 8 + (ch & 7)];
                wb[ch] = w1t[((d0 + 1) * 7 + k) * 8 + (ch & 7)];
            }
#pragma unroll
            for (int m = 0; m < 5; ++m) {
                float4 v = rowsW[tA[m] + 2 + k];   // t-6+k, +8 guard offset
#pragma unroll
                for (int ch = 0; ch < 16; ++ch) {
                    float x0 = (ch < 8) ? v.x : v.z;
                    float x1 = (ch < 8) ? v.y : v.w;
                    acc[ch][m] = fmaf(wa[ch], x0, acc[ch][m]);
                    acc[ch][m] = fmaf(wb[ch], x1, acc[ch][m]);
                }
            }
        }

        // ---- p1 guards (rows region is dead now; p1 aliases it) ----
#pragma unroll
        for (int i = lane; i < 128; i += 64) {
            int c = i >> 3, j = i & 7;
            int pos = (j < 4) ? j : (131 + j);
            p1w[c * 140 + pos] = 0.f;
        }

        // ---- exact order-preserving top-131 per channel, 2 channels interleaved ----
        // 16-bit early-exit radix: keep-set provably identical to full 32-bit select.
        // chp loop FULLY UNROLLED so acc[] indices stay compile-time (no scratch).
#pragma unroll
        for (int chp = 0; chp < 16; chp += 2) {
            uint32_t uA[5], uB[5];
#pragma unroll
            for (int m = 0; m < 5; ++m) {
                int t = lane + 64 * m;
                uA[m] = (t < OUT1) ? f2ord(acc[chp][m])     : 0u;   // sentinel = minimum
                uB[m] = (t < OUT1) ? f2ord(acc[chp + 1][m]) : 0u;
            }
            uint32_t preA = 0, preB = 0;
#pragma unroll 1
            for (int bit = 31; bit >= 16; --bit) {
                uint32_t cA = preA | (1u << bit);
                uint32_t cB = preB | (1u << bit);
                int na = 0, nb = 0;
#pragma unroll
                for (int m = 0; m < 5; ++m) {
                    na += __popcll(__ballot(uA[m] >= cA));
                    nb += __popcll(__ballot(uB[m] >= cB));
                }
                if (na >= K1SEL) preA = cA;
                if (nb >= K1SEL) preB = cB;
            }
            // prefix-level counts: gX = #(>prefix), eX = #(==prefix)
            int gA = 0, gB = 0, eA = 0, eB = 0;
            uint32_t pA16 = preA >> 16, pB16 = preB >> 16;
#pragma unroll
            for (int m = 0; m < 5; ++m) {
                gA += __popcll(__ballot((uA[m] >> 16) >  pA16));
                eA += __popcll(__ballot((uA[m] >> 16) == pA16));
                gB += __popcll(__ballot((uB[m] >> 16) >  pB16));
                eB += __popcll(__ballot((uB[m] >> 16) == pB16));
            }
            uint32_t maskA = 0xFFFF0000u, maskB = 0xFFFF0000u;
            if ((K1SEL - gA < eA) || (K1SEL - gB < eB)) {
                // boundary collision in top-16 bits: refine low 16 bits (both channels)
#pragma unroll 1
                for (int bit = 15; bit >= 0; --bit) {
                    uint32_t cA = preA | (1u << bit);
                    uint32_t cB = preB | (1u << bit);
                    int na = 0, nb = 0;
#pragma unroll
                    for (int m = 0; m < 5; ++m) {
                        na += __popcll(__ballot(uA[m] >= cA));
                        nb += __popcll(__ballot(uB[m] >= cB));
                    }
                    if (na >= K1SEL) preA = cA;
                    if (nb >= K1SEL) preB = cB;
                }
                maskA = maskB = 0xFFFFFFFFu;
            }
            int cgtA = 0, cgtB = 0;
#pragma unroll
            for (int m = 0; m < 5; ++m) {
                cgtA += __popcll(__ballot((uA[m] & maskA) > preA));
                cgtB += __popcll(__ballot((uB[m] & maskB) > preB));
            }
            const int needA = K1SEL - cgtA;            // #ties to keep (earliest t first)
            const int needB = K1SEL - cgtB;
            float* dstA = p1w + chp * 140 + 4;
            float* dstB = p1w + (chp + 1) * 140 + 4;
            int eqA = 0, kpA = 0, eqB = 0, kpB = 0;
#pragma unroll
            for (int m = 0; m < 5; ++m) {
                unsigned long long emA = __ballot((uA[m] & maskA) == preA);
                unsigned long long emB = __ballot((uB[m] & maskB) == preB);
                int erA = eqA + lane_prefix(emA);
                int erB = eqB + lane_prefix(emB);
                bool keepA = ((uA[m] & maskA) > preA) || (((uA[m] & maskA) == preA) && (erA < needA));
                bool keepB = ((uB[m] & maskB) > preB) || (((uB[m] & maskB) == preB) && (erB < needB));
                unsigned long long kmA = __ballot(keepA);
                unsigned long long kmB = __ballot(keepB);
                int posA = kpA + lane_prefix(kmA);     // order-preserving compaction
                int posB = kpB + lane_prefix(kmB);
                if (keepA) dstA[posA] = fast_tanh(acc[chp][m]);
                if (keepB) dstB[posB] = fast_tanh(acc[chp + 1][m]);
                eqA += __popcll(emA); kpA += __popcll(kmA);
                eqB += __popcll(emB); kpB += __popcll(kmB);
            }
        }

        // ---- conv2 (K=5, 8-in/16-out per group) over both groups + fold ----
        float a2[16][3];
#pragma unroll
        for (int f2 = 0; f2 < 16; ++f2) {
            float bz = b2c[r3 * 16 + f2];
            a2[f2][0] = bz; a2[f2][1] = bz; a2[f2][2] = bz;
        }
        int tB[3];
#pragma unroll
        for (int tm = 0; tm < 3; ++tm) { int t = lane + 64 * tm; tB[tm] = (t < OUT2) ? t : (OUT2 - 1); }

#pragma unroll 1
        for (int rs = 0; rs < 2; ++rs) {
            const int g = 2 * r3 + rs;
#pragma unroll 1
            for (int ic = 0; ic < 8; ++ic) {
                const float* src = p1w + (rs * 8 + ic) * 140;   // logical t' = idx - 4
#pragma unroll
                for (int k = 0; k < 5; ++k) {
                    float v0 = src[tB[0] + k];          // t + k - 4, +4 guard
                    float v1 = src[tB[1] + k];
                    float v2 = src[tB[2] + k];
                    const float* wp = &w2t[((g * 8 + ic) * 5 + k) * 16];
#pragma unroll
                    for (int f2 = 0; f2 < 16; ++f2) {
                        float w = wp[f2];
                        a2[f2][0] = fmaf(w, v0, a2[f2][0]);
                        a2[f2][1] = fmaf(w, v1, a2[f2][1]);
                        a2[f2][2] = fmaf(w, v2, a2[f2][2]);
                    }
                }
            }
        }

        // ---- top-4 (value desc, tie -> lower t), then emit in t order, tanh ----
#pragma unroll
        for (int f2 = 0; f2 < 16; ++f2) {
            uint32_t u0 = f2ord(a2[f2][0]);                          // t=lane < 135 always
            uint32_t u1 = f2ord(a2[f2][1]);                          // t=lane+64 < 135 always
            uint32_t u2 = (lane + 128 < OUT2) ? f2ord(a2[f2][2]) : 0u;
            int   wt[4]; float wvv[4];
#pragma unroll
            for (int j = 0; j < 4; ++j) {
                uint32_t loc = max(u0, max(u1, u2));
#pragma unroll
                for (int off = 32; off > 0; off >>= 1)
                    loc = max(loc, (uint32_t)__shfl_xor((int)loc, off, 64));
                unsigned long long m0 = __ballot(u0 == loc);
                unsigned long long m1 = __ballot(u1 == loc);
                unsigned long long m2 = __ballot(u2 == loc);
                int t;
                if (m0)      t = __builtin_ctzll(m0);
                else if (m1) t = 64 + __builtin_ctzll(m1);
                else         t = 128 + __builtin_ctzll(m2);
                wt[j] = t; wvv[j] = ord2f(loc);
                if (t < 64)       { if (lane == t)       u0 = 0; }
                else if (t < 128) { if (lane == t - 64)  u1 = 0; }
                else              { if (lane == t - 128) u2 = 0; }
            }
            // sort the 4 winners by t ascending (order-preserving)
#define CSW(i, jj) { if (wt[i] > wt[jj]) { int tt = wt[i]; wt[i] = wt[jj]; wt[jj] = tt; \
                                           float vv = wvv[i]; wvv[i] = wvv[jj]; wvv[jj] = vv; } }
            CSW(0, 1); CSW(2, 3); CSW(0, 2); CSW(1, 3); CSW(1, 2);
#undef CSW
            if (lane == 0) {
                float* q = &p2[(r3 * 16 + f2) * 4];
                q[0] = fast_tanh(wvv[0]); q[1] = fast_tanh(wvv[1]);
                q[2] = fast_tanh(wvv[2]); q[3] = fast_tanh(wvv[3]);
            }
        }
    }

    __syncthreads();

    // ---- FC: (1024) @ (6,1024)^T + b ----
    float part[6] = {0.f, 0.f, 0.f, 0.f, 0.f, 0.f};
#pragma unroll
    for (int r = 0; r < 2; ++r) {
        int i = tid + 512 * r;
        float pv = p2[i];
#pragma unroll
        for (int n = 0; n < 6; ++n) part[n] = fmaf(pv, fcw[n * 1024 + i], part[n]);
    }
#pragma unroll
    for (int n = 0; n < 6; ++n) {
        float s = part[n];
#pragma unroll
        for (int off = 32; off > 0; off >>= 1) s += __shfl_xor(s, off, 64);
        if (lane == 0) fred[wv][n] = s;
    }
    __syncthreads();
    if (tid < 6) {
        float s = fcb[tid];
#pragma unroll
        for (int w = 0; w < 8; ++w) s += fred[w][tid];
        out[b * 6 + tid] = s;
    }
}

extern "C" void kernel_launch(void* const* d_in, const int* in_sizes, int n_in,
                              void* d_out, int out_size, void* d_ws, size_t ws_size,
                              hipStream_t stream) {
    (void)in_sizes; (void)n_in; (void)out_size; (void)ws_size;
    const int*   x   = (const int*)d_in[0];
    const float* emb = (const float*)d_in[1];
    const float* w1  = (const float*)d_in[2];
    const float* b1  = (const float*)d_in[3];
    const float* w2  = (const float*)d_in[4];
    const float* b2  = (const float*)d_in[5];
    const float* fcw = (const float*)d_in[6];
    const float* fcb = (const float*)d_in[7];
    float* outp = (float*)d_out;
    float* ws   = (float*)d_ws;

    dcnn_prep<<<96, 256, 0, stream>>>(w1, b1, w2, b2, ws);   // 24576 elems, 1 thread each
    dcnn_main<<<512, 512, 0, stream>>>(x, emb, fcw, fcb, ws, outp);
}

// Round 6
// 250.542 us; speedup vs baseline: 1.1202x; 1.1202x over previous
//
#include <hip/hip_runtime.h>
#include <stdint.h>

// ---------------- problem constants ----------------
#define S_LEN 256
#define OUT1  262      // S + 7 - 1
#define K1SEL 131      // ceil((2-1)/2 * 262)
#define OUT2  135      // 131 + 5 - 1
// ws layout (floats)
#define W1T_OFF 0          // w1t[d][k][f]      64*7*8   = 3584
#define W2T_OFF 3584       // w2t[g][ic][k][f2] 32*8*5*16= 20480
#define B1C_OFF 24064      // b1c[r2][f]        32*8
#define B2C_OFF 24320      // b2c[r3][f2]       16*16
#define WS_FLOATS 24576

__device__ __forceinline__ int lane_prefix(unsigned long long m) {
    return __builtin_amdgcn_mbcnt_hi((uint32_t)(m >> 32),
           __builtin_amdgcn_mbcnt_lo((uint32_t)m, 0));
}
__device__ __forceinline__ uint32_t f2ord(float x) {
    uint32_t b = __float_as_uint(x);
    return (b & 0x80000000u) ? ~b : (b | 0x80000000u);
}
__device__ __forceinline__ float ord2f(uint32_t s) {
    uint32_t b = (s & 0x80000000u) ? (s & 0x7FFFFFFFu) : ~s;
    return __uint_as_float(b);
}
__device__ __forceinline__ float fast_tanh(float x) {
    float e = __expf(2.0f * x);
    return (e - 1.0f) / (e + 1.0f);
}
typedef unsigned long long u64;
__device__ __forceinline__ u64 shflx64(u64 v, int m) {
    uint32_t lo = (uint32_t)__shfl_xor((int)(uint32_t)v, m, 64);
    uint32_t hi = (uint32_t)__shfl_xor((int)(uint32_t)(v >> 32), m, 64);
    return ((u64)hi << 32) | lo;
}
__device__ __forceinline__ u64 maxu64(u64 a, u64 b) { return a > b ? a : b; }
__device__ __forceinline__ u64 minu64(u64 a, u64 b) { return a < b ? a : b; }

// ------------- prep: transpose weights / fold biases into ws -------------
extern "C" __global__ void dcnn_prep(const float* __restrict__ w1, const float* __restrict__ b1,
                                     const float* __restrict__ w2, const float* __restrict__ b2,
                                     float* __restrict__ ws) {
    int i = blockIdx.x * 256 + threadIdx.x;   // 96*256 == 24576 == WS_FLOATS
    if (i < W2T_OFF) {                        // w1t[d][k][f] = w1[(d*8+f)*7 + k]
        int d = i / 56, r = i % 56, k = r / 8, f = r % 8;
        ws[i] = w1[(d * 8 + f) * 7 + k];
    } else if (i < B1C_OFF) {                 // w2t[g][ic][k][f2] = w2[((g*16+f2)*8+ic)*5+k]
        int q = i - W2T_OFF;
        int g = q / 640, r = q % 640;
        int ic = r / 80, r2 = r % 80;
        int k = r2 / 16, f2 = r2 % 16;
        ws[i] = w2[((g * 16 + f2) * 8 + ic) * 5 + k];
    } else if (i < B2C_OFF) {                 // b1c[r2][f] = b1[2r2*8+f] + b1[(2r2+1)*8+f]
        int q = i - B1C_OFF;
        int r2 = q / 8, f = q % 8;
        ws[i] = b1[(2 * r2) * 8 + f] + b1[(2 * r2 + 1) * 8 + f];
    } else {                                  // b2c[r3][f2]
        int q = i - B2C_OFF;
        int r3 = q / 16, f2 = q % 16;
        ws[i] = b2[(2 * r3) * 16 + f2] + b2[(2 * r3 + 1) * 16 + f2];
    }
}

// ------------- main: one block (512 thr, 8 waves) per sample, 2 r3-slices/wave -------------
// LDS: per-wave union region (2240 floats = 8960 B):
//   phase A (conv1 input): rows = float4[272], idx t+8, zero guards at 0..7 & 264..271
//   phase B (conv2 input): p1[2][8][140], data at pos+4, zero guards 0..3 & 135..138
//   phase C (top4 scratch): a2 dump [f2:16][137]
// Safe: each phase fully consumes the previous within the same wave (program order).
//
// Register lessons (R2-R5): __launch_bounds__(512,4) => hard 64-VGPR cap (spills);
// compiler settles at 64 arch VGPR + AGPRs via the unified file. Select-1 channel
// loop MUST stay fully unrolled (runtime index into acc[16][5] => ~300 MB scratch
// spill traffic, measured R2/R3).
extern "C" __global__
__attribute__((amdgpu_flat_work_group_size(512, 512), amdgpu_waves_per_eu(4, 4)))
void dcnn_main(const int* __restrict__ x, const float* __restrict__ emb,
               const float* __restrict__ fcw, const float* __restrict__ fcb,
               const float* __restrict__ ws, float* __restrict__ out) {
    __shared__ float uni[8][2240];        // 71680 B
    __shared__ int   xs[S_LEN];           // 1 KB
    __shared__ float p2[1024];            // 4 KB : [ (r3*16+f2)*4 + j ]  (raw, pre-tanh)
    __shared__ float fred[8][6];

    const int b    = blockIdx.x;
    const int tid  = threadIdx.x;
    const int lane = tid & 63;
    const int wv   = __builtin_amdgcn_readfirstlane(tid >> 6);

    const float* w1t = ws + W1T_OFF;
    const float* w2t = ws + W2T_OFF;
    const float* b1c = ws + B1C_OFF;
    const float* b2c = ws + B2C_OFF;

    if (tid < S_LEN) xs[tid] = x[b * S_LEN + tid];
    __syncthreads();

    float4* rowsW = (float4*)&uni[wv][0];   // 272 float4 = 1088 floats
    float*  p1w   = &uni[wv][0];            // [ch:16][140], ch = rs*8+f

#pragma unroll 1
    for (int it = 0; it < 2; ++it) {
        const int r3 = wv * 2 + it;

        // ---- guards + stage 4 embedding rows (d = 4r3..4r3+3) as float4 per t ----
        if (lane < 16) rowsW[(lane < 8) ? lane : (256 + lane)] = make_float4(0.f, 0.f, 0.f, 0.f);
#pragma unroll
        for (int m = 0; m < 4; ++m) {
            int t = lane + 64 * m;
            int xi = xs[t];
            float4 v = *(const float4*)(emb + (size_t)xi * 64 + 4 * r3);
            rowsW[8 + t] = v;
        }

        // ---- conv1 (K=7, depthwise) + fold: 16 channels (rs*8+f), t = lane+64m ----
        float acc[16][5];
#pragma unroll
        for (int ch = 0; ch < 16; ++ch) {
            float bz = b1c[(2 * r3 + (ch >> 3)) * 8 + (ch & 7)];
#pragma unroll
            for (int m = 0; m < 5; ++m) acc[ch][m] = bz;
        }
        int tA[5];
#pragma unroll
        for (int m = 0; m < 5; ++m) { int t = lane + 64 * m; tA[m] = (t < OUT1) ? t : (OUT1 - 1); }

#pragma unroll 1
        for (int k = 0; k < 7; ++k) {
            float wa[16], wb[16];
#pragma unroll
            for (int ch = 0; ch < 16; ++ch) {
                int d0 = 4 * r3 + 2 * (ch >> 3);
                wa[ch] = w1t[(d0 * 7 + k) * 8 + (ch & 7)];
                wb[ch] = w1t[((d0 + 1) * 7 + k) * 8 + (ch & 7)];
            }
#pragma unroll
            for (int m = 0; m < 5; ++m) {
                float4 v = rowsW[tA[m] + 2 + k];   // t-6+k, +8 guard offset
#pragma unroll
                for (int ch = 0; ch < 16; ++ch) {
                    float x0 = (ch < 8) ? v.x : v.z;
                    float x1 = (ch < 8) ? v.y : v.w;
                    acc[ch][m] = fmaf(wa[ch], x0, acc[ch][m]);
                    acc[ch][m] = fmaf(wb[ch], x1, acc[ch][m]);
                }
            }
        }

        // ---- p1 guards (rows region is dead now; p1 aliases it) ----
#pragma unroll
        for (int i = lane; i < 128; i += 64) {
            int c = i >> 3, j = i & 7;
            int pos = (j < 4) ? j : (131 + j);
            p1w[c * 140 + pos] = 0.f;
        }

        // ---- exact order-preserving top-131 per channel, 2 channels interleaved ----
        // 16-bit early-exit radix: keep-set provably identical to full 32-bit select.
        // chp loop FULLY UNROLLED so acc[] indices stay compile-time (no scratch).
#pragma unroll
        for (int chp = 0; chp < 16; chp += 2) {
            uint32_t uA[5], uB[5];
#pragma unroll
            for (int m = 0; m < 5; ++m) {
                int t = lane + 64 * m;
                uA[m] = (t < OUT1) ? f2ord(acc[chp][m])     : 0u;   // sentinel = minimum
                uB[m] = (t < OUT1) ? f2ord(acc[chp + 1][m]) : 0u;
            }
            uint32_t preA = 0, preB = 0;
#pragma unroll 1
            for (int bit = 31; bit >= 16; --bit) {
                uint32_t cA = preA | (1u << bit);
                uint32_t cB = preB | (1u << bit);
                int na = 0, nb = 0;
#pragma unroll
                for (int m = 0; m < 5; ++m) {
                    na += __popcll(__ballot(uA[m] >= cA));
                    nb += __popcll(__ballot(uB[m] >= cB));
                }
                if (na >= K1SEL) preA = cA;
                if (nb >= K1SEL) preB = cB;
            }
            // prefix-level counts: gX = #(>prefix), eX = #(==prefix)
            int gA = 0, gB = 0, eA = 0, eB = 0;
            uint32_t pA16 = preA >> 16, pB16 = preB >> 16;
#pragma unroll
            for (int m = 0; m < 5; ++m) {
                gA += __popcll(__ballot((uA[m] >> 16) >  pA16));
                eA += __popcll(__ballot((uA[m] >> 16) == pA16));
                gB += __popcll(__ballot((uB[m] >> 16) >  pB16));
                eB += __popcll(__ballot((uB[m] >> 16) == pB16));
            }
            uint32_t maskA = 0xFFFF0000u, maskB = 0xFFFF0000u;
            if ((K1SEL - gA < eA) || (K1SEL - gB < eB)) {
                // boundary collision in top-16 bits: refine low 16 bits (both channels)
#pragma unroll 1
                for (int bit = 15; bit >= 0; --bit) {
                    uint32_t cA = preA | (1u << bit);
                    uint32_t cB = preB | (1u << bit);
                    int na = 0, nb = 0;
#pragma unroll
                    for (int m = 0; m < 5; ++m) {
                        na += __popcll(__ballot(uA[m] >= cA));
                        nb += __popcll(__ballot(uB[m] >= cB));
                    }
                    if (na >= K1SEL) preA = cA;
                    if (nb >= K1SEL) preB = cB;
                }
                maskA = maskB = 0xFFFFFFFFu;
            }
            int cgtA = 0, cgtB = 0;
#pragma unroll
            for (int m = 0; m < 5; ++m) {
                cgtA += __popcll(__ballot((uA[m] & maskA) > preA));
                cgtB += __popcll(__ballot((uB[m] & maskB) > preB));
            }
            const int needA = K1SEL - cgtA;            // #ties to keep (earliest t first)
            const int needB = K1SEL - cgtB;
            float* dstA = p1w + chp * 140 + 4;
            float* dstB = p1w + (chp + 1) * 140 + 4;
            int eqA = 0, kpA = 0, eqB = 0, kpB = 0;
#pragma unroll
            for (int m = 0; m < 5; ++m) {
                unsigned long long emA = __ballot((uA[m] & maskA) == preA);
                unsigned long long emB = __ballot((uB[m] & maskB) == preB);
                int erA = eqA + lane_prefix(emA);
                int erB = eqB + lane_prefix(emB);
                bool keepA = ((uA[m] & maskA) > preA) || (((uA[m] & maskA) == preA) && (erA < needA));
                bool keepB = ((uB[m] & maskB) > preB) || (((uB[m] & maskB) == preB) && (erB < needB));
                unsigned long long kmA = __ballot(keepA);
                unsigned long long kmB = __ballot(keepB);
                int posA = kpA + lane_prefix(kmA);     // order-preserving compaction
                int posB = kpB + lane_prefix(kmB);
                if (keepA) dstA[posA] = fast_tanh(acc[chp][m]);
                if (keepB) dstB[posB] = fast_tanh(acc[chp + 1][m]);
                eqA += __popcll(emA); kpA += __popcll(kmA);
                eqB += __popcll(emB); kpB += __popcll(kmB);
            }
        }

        // ---- conv2 (K=5, 8-in/16-out per group) over both groups + fold ----
        float a2[16][3];
#pragma unroll
        for (int f2 = 0; f2 < 16; ++f2) {
            float bz = b2c[r3 * 16 + f2];
            a2[f2][0] = bz; a2[f2][1] = bz; a2[f2][2] = bz;
        }
        int tB[3];
#pragma unroll
        for (int tm = 0; tm < 3; ++tm) { int t = lane + 64 * tm; tB[tm] = (t < OUT2) ? t : (OUT2 - 1); }

#pragma unroll 1
        for (int rs = 0; rs < 2; ++rs) {
            const int g = 2 * r3 + rs;
#pragma unroll 1
            for (int ic = 0; ic < 8; ++ic) {
                const float* src = p1w + (rs * 8 + ic) * 140;   // logical t' = idx - 4
#pragma unroll
                for (int k = 0; k < 5; ++k) {
                    float v0 = src[tB[0] + k];          // t + k - 4, +4 guard
                    float v1 = src[tB[1] + k];
                    float v2 = src[tB[2] + k];
                    const float* wp = &w2t[((g * 8 + ic) * 5 + k) * 16];
#pragma unroll
                    for (int f2 = 0; f2 < 16; ++f2) {
                        float w = wp[f2];
                        a2[f2][0] = fmaf(w, v0, a2[f2][0]);
                        a2[f2][1] = fmaf(w, v1, a2[f2][1]);
                        a2[f2][2] = fmaf(w, v2, a2[f2][2]);
                    }
                }
            }
        }

        // ---- top-4 (value desc, tie -> lower t), wave-parallel LDS scan ----
        // p1 region is dead after conv2; reuse as scratch[f2:16][137] (pad -> bank spread).
        // 64-bit key = (f2ord(v)<<32) | (0xFFFFFFFF - t): desc order == value desc, tie t asc.
        {
            float* scr = p1w;
#pragma unroll
            for (int f2 = 0; f2 < 16; ++f2) {
                scr[f2 * 137 + lane]      = a2[f2][0];
                scr[f2 * 137 + lane + 64] = a2[f2][1];
                if (lane + 128 < OUT2) scr[f2 * 137 + lane + 128] = a2[f2][2];
            }
            const int f2o = lane >> 2, q = lane & 3;
            const float* src = scr + f2o * 137 + q * 34;
            const int tend = (q == 3) ? (OUT2 - 102) : 34;   // 34,34,34,33
            const uint32_t tbase = 0xFFFFFFFFu - (uint32_t)(q * 34);
            u64 L0 = 0, L1 = 0, L2 = 0, L3 = 0;             // sentinels (lose to any finite)
#pragma unroll 2
            for (int i = 0; i < 34; ++i) {
                float v = src[(i < tend) ? i : 0];
                u64 k = ((u64)f2ord(v) << 32) | (u64)(tbase - (uint32_t)i);
                if (i >= tend) k = 0;
                bool b0 = k > L0, b1 = k > L1, b2 = k > L2, b3 = k > L3;
                L3 = b3 ? (b2 ? L2 : k) : L3;
                L2 = b2 ? (b1 ? L1 : k) : L2;
                L1 = b1 ? (b0 ? L0 : k) : L1;
                L0 = b0 ? k : L0;
            }
            // merge the 4 quarters: 2 shfl rounds; r_i = min_{j+l=i} max(A_j,B_l)
#pragma unroll
            for (int d = 1; d <= 2; d <<= 1) {
                u64 M0 = shflx64(L0, d), M1 = shflx64(L1, d);
                u64 M2 = shflx64(L2, d), M3 = shflx64(L3, d);
                u64 r0 = maxu64(L0, M0);
                u64 r1 = minu64(maxu64(L0, M1), maxu64(L1, M0));
                u64 r2 = minu64(minu64(maxu64(L0, M2), maxu64(L1, M1)), maxu64(L2, M0));
                u64 r3k = minu64(minu64(maxu64(L0, M3), maxu64(L1, M2)),
                                 minu64(maxu64(L2, M1), maxu64(L3, M0)));
                L0 = r0; L1 = r1; L2 = r2; L3 = r3k;
            }
            if (q == 0) {
                // reorder by t ascending == low-32 word descending; emit RAW (tanh in FC)
#define CSW2(a, bb) { if ((uint32_t)(bb) > (uint32_t)(a)) { u64 tt = (a); (a) = (bb); (bb) = tt; } }
                CSW2(L0, L1); CSW2(L2, L3); CSW2(L0, L2); CSW2(L1, L3); CSW2(L1, L2);
#undef CSW2
                float* qp = &p2[(r3 * 16 + f2o) * 4];
                qp[0] = ord2f((uint32_t)(L0 >> 32));
                qp[1] = ord2f((uint32_t)(L1 >> 32));
                qp[2] = ord2f((uint32_t)(L2 >> 32));
                qp[3] = ord2f((uint32_t)(L3 >> 32));
            }
        }
    }

    __syncthreads();

    // ---- FC: tanh(p2) @ (6,1024)^T + b  (tanh applied here, 2/thread) ----
    float part[6] = {0.f, 0.f, 0.f, 0.f, 0.f, 0.f};
#pragma unroll
    for (int r = 0; r < 2; ++r) {
        int i = tid + 512 * r;
        float pv = fast_tanh(p2[i]);
#pragma unroll
        for (int n = 0; n < 6; ++n) part[n] = fmaf(pv, fcw[n * 1024 + i], part[n]);
    }
#pragma unroll
    for (int n = 0; n < 6; ++n) {
        float s = part[n];
#pragma unroll
        for (int off = 32; off > 0; off >>= 1) s += __shfl_xor(s, off, 64);
        if (lane == 0) fred[wv][n] = s;
    }
    __syncthreads();
    if (tid < 6) {
        float s = fcb[tid];
#pragma unroll
        for (int w = 0; w < 8; ++w) s += fred[w][tid];
        out[b * 6 + tid] = s;
    }
}

extern "C" void kernel_launch(void* const* d_in, const int* in_sizes, int n_in,
                              void* d_out, int out_size, void* d_ws, size_t ws_size,
                              hipStream_t stream) {
    (void)in_sizes; (void)n_in; (void)out_size; (void)ws_size;
    const int*   x   = (const int*)d_in[0];
    const float* emb = (const float*)d_in[1];
    const float* w1  = (const float*)d_in[2];
    const float* b1  = (const float*)d_in[3];
    const float* w2  = (const float*)d_in[4];
    const float* b2  = (const float*)d_in[5];
    const float* fcw = (const float*)d_in[6];
    const float* fcb = (const float*)d_in[7];
    float* outp = (float*)d_out;
    float* ws   = (float*)d_ws;

    dcnn_prep<<<96, 256, 0, stream>>>(w1, b1, w2, b2, ws);   // 24576 elems, 1 thread each
    dcnn_main<<<512, 512, 0, stream>>>(x, emb, fcw, fcb, ws, outp);
}

// Round 7
// 242.650 us; speedup vs baseline: 1.1566x; 1.0325x over previous
//
#include <hip/hip_runtime.h>
#include <stdint.h>

// ---------------- problem constants ----------------
#define S_LEN 256
#define OUT1  262      // S + 7 - 1
#define K1SEL 131      // ceil((2-1)/2 * 262)
#define OUT2  135      // 131 + 5 - 1
// ws layout (floats)
#define W1T_OFF 0          // w1t[d][k][f]      64*7*8   = 3584
#define W2T_OFF 3584       // w2t[g][ic][k][f2] 32*8*5*16= 20480
#define B1C_OFF 24064      // b1c[r2][f]        32*8
#define B2C_OFF 24320      // b2c[r3][f2]       16*16
#define FCP_OFF 24576      // per-block FC partials: 2048*6 floats (needs ws >= 148 KB)
#define WREG    1120       // floats per wave LDS region

__device__ __forceinline__ int lane_prefix(unsigned long long m) {
    return __builtin_amdgcn_mbcnt_hi((uint32_t)(m >> 32),
           __builtin_amdgcn_mbcnt_lo((uint32_t)m, 0));
}
__device__ __forceinline__ uint32_t f2ord(float x) {
    uint32_t b = __float_as_uint(x);
    return (b & 0x80000000u) ? ~b : (b | 0x80000000u);
}
__device__ __forceinline__ float ord2f(uint32_t s) {
    uint32_t b = (s & 0x80000000u) ? (s & 0x7FFFFFFFu) : ~s;
    return __uint_as_float(b);
}
__device__ __forceinline__ float fast_tanh(float x) {
    float e = __expf(2.0f * x);
    return (e - 1.0f) / (e + 1.0f);
}
typedef unsigned long long u64;
__device__ __forceinline__ u64 shflx64(u64 v, int m) {
    uint32_t lo = (uint32_t)__shfl_xor((int)(uint32_t)v, m, 64);
    uint32_t hi = (uint32_t)__shfl_xor((int)(uint32_t)(v >> 32), m, 64);
    return ((u64)hi << 32) | lo;
}
__device__ __forceinline__ u64 maxu64(u64 a, u64 b) { return a > b ? a : b; }
__device__ __forceinline__ u64 minu64(u64 a, u64 b) { return a < b ? a : b; }

// ------------- prep: transpose weights / fold biases into ws -------------
extern "C" __global__ void dcnn_prep(const float* __restrict__ w1, const float* __restrict__ b1,
                                     const float* __restrict__ w2, const float* __restrict__ b2,
                                     float* __restrict__ ws) {
    int i = blockIdx.x * 256 + threadIdx.x;   // 96*256 == 24576
    if (i < W2T_OFF) {                        // w1t[d][k][f] = w1[(d*8+f)*7 + k]
        int d = i / 56, r = i % 56, k = r / 8, f = r % 8;
        ws[i] = w1[(d * 8 + f) * 7 + k];
    } else if (i < B1C_OFF) {                 // w2t[g][ic][k][f2] = w2[((g*16+f2)*8+ic)*5+k]
        int q = i - W2T_OFF;
        int g = q / 640, r = q % 640;
        int ic = r / 80, r2 = r % 80;
        int k = r2 / 16, f2 = r2 % 16;
        ws[i] = w2[((g * 16 + f2) * 8 + ic) * 5 + k];
    } else if (i < B2C_OFF) {                 // b1c[r2][f] = b1[2r2*8+f] + b1[(2r2+1)*8+f]
        int q = i - B1C_OFF;
        int r2 = q / 8, f = q % 8;
        ws[i] = b1[(2 * r2) * 8 + f] + b1[(2 * r2 + 1) * 8 + f];
    } else {                                  // b2c[r3][f2]
        int q = i - B2C_OFF;
        int r3 = q / 16, f2 = q % 16;
        ws[i] = b2[(2 * r3) * 16 + f2] + b2[(2 * r3 + 1) * 16 + f2];
    }
}

// ------------- main: one wave = one (slice, rs-half) task -------------
// Block = 512 thr (8 waves) = 4 slices x 2 rs-halves of ONE sample; grid 2048.
// Fold separability: conv1 channel (rs,f) needs emb rows 4sl+2rs(+1) only;
// conv2 group g=2sl+rs needs only that half's 8 p1 channels. Only the a2 fold
// couples the halves -> done in the pair's dead p1 LDS with block syncs.
// Per-wave LDS region (WREG=1120 floats):
//   phase A: rows float2[272] (inputs at j+8, zero guards 0..7 & 264..271)
//   phase B: p1[8][140] (data at +4, zero guards 0..3 & 135..138)
//   phase C (pair, 2240 floats): a2 sum + top4 scratch [f2:16][137]
// LDS/block ~38 KB -> 4 blocks/CU by LDS; waves_per_eu(6,8) targets ~80 VGPRs
// (safe: acc[8][5]=40, a2[16][3]=48) -> >=24 waves/CU vs R6's 16.
// R3 lesson: select channel loop fully unrolled (runtime index into acc => scratch spill).
extern "C" __global__
__attribute__((amdgpu_flat_work_group_size(512, 512), amdgpu_waves_per_eu(6, 8)))
void dcnn_main(const int* __restrict__ x, const float* __restrict__ emb,
               const float* __restrict__ fcw, float* __restrict__ ws) {
    __shared__ float uni[8 * WREG];       // 35840 B
    __shared__ int   xs[S_LEN];           // 1 KB
    __shared__ float p2loc[256];          // this block's 256 FC features (raw, pre-tanh)
    __shared__ float fred[4][6];

    const int tid    = threadIdx.x;
    const int lane   = tid & 63;
    const int wv     = __builtin_amdgcn_readfirstlane(tid >> 6);
    const int sample = blockIdx.x >> 2;
    const int q4     = blockIdx.x & 3;
    const int sl     = q4 * 4 + (wv >> 1);   // global slice r3 in [0,16)
    const int rs     = wv & 1;               // which half of the fold pair

    const float* w1t = ws + W1T_OFF;
    const float* w2t = ws + W2T_OFF;
    const float* b1c = ws + B1C_OFF;
    const float* b2c = ws + B2C_OFF;

    if (tid < S_LEN) xs[tid] = x[sample * S_LEN + tid];
    __syncthreads();

    float*  reg   = uni + wv * WREG;
    float2* rowsW = (float2*)reg;          // 272 float2 = 544 floats
    float*  p1w   = reg;                   // [f:8][140]

    // ---- guards + stage 2 embedding rows (d = 4sl+2rs, +1) as float2 per j ----
    if (lane < 8) {
        rowsW[lane]       = make_float2(0.f, 0.f);
        rowsW[264 + lane] = make_float2(0.f, 0.f);
    }
    const int dbase = 4 * sl + 2 * rs;
#pragma unroll
    for (int m = 0; m < 4; ++m) {
        int j  = lane + 64 * m;            // input pos 0..255
        int xi = xs[j];
        rowsW[8 + j] = *(const float2*)(emb + (size_t)xi * 64 + dbase);
    }

    // ---- conv1 (K=7, depthwise) + fold: 8 channels f, t = lane+64m ----
    float acc[8][5];
#pragma unroll
    for (int f = 0; f < 8; ++f) {
        float bz = b1c[(2 * sl + rs) * 8 + f];
#pragma unroll
        for (int m = 0; m < 5; ++m) acc[f][m] = bz;
    }
    int tA[5];
#pragma unroll
    for (int m = 0; m < 5; ++m) { int t = lane + 64 * m; tA[m] = (t < OUT1) ? t : (OUT1 - 1); }

#pragma unroll 1
    for (int k = 0; k < 7; ++k) {
        float wa[8], wb[8];
#pragma unroll
        for (int f = 0; f < 8; ++f) {
            wa[f] = w1t[(dbase * 7 + k) * 8 + f];
            wb[f] = w1t[((dbase + 1) * 7 + k) * 8 + f];
        }
#pragma unroll
        for (int m = 0; m < 5; ++m) {
            float2 v = rowsW[tA[m] + 2 + k];   // j = t-6+k, +8 guard offset
#pragma unroll
            for (int f = 0; f < 8; ++f) {
                acc[f][m] = fmaf(wa[f], v.x, acc[f][m]);
                acc[f][m] = fmaf(wb[f], v.y, acc[f][m]);
            }
        }
    }

    // ---- p1 guards (rows region dead; p1 aliases it). 64 lanes = 8 ch x 8 slots ----
    {
        int c = lane >> 3, j = lane & 7;
        int pos = (j < 4) ? j : (131 + j);
        p1w[c * 140 + pos] = 0.f;
    }

    // ---- exact order-preserving top-131 per channel, 2 channels interleaved ----
    // 16-bit early-exit radix; keep-set provably identical to full 32-bit select.
#pragma unroll
    for (int chp = 0; chp < 8; chp += 2) {
        uint32_t uA[5], uB[5];
#pragma unroll
        for (int m = 0; m < 5; ++m) {
            int t = lane + 64 * m;
            uA[m] = (t < OUT1) ? f2ord(acc[chp][m])     : 0u;   // sentinel = minimum
            uB[m] = (t < OUT1) ? f2ord(acc[chp + 1][m]) : 0u;
        }
        uint32_t preA = 0, preB = 0;
#pragma unroll 1
        for (int bit = 31; bit >= 16; --bit) {
            uint32_t cA = preA | (1u << bit);
            uint32_t cB = preB | (1u << bit);
            int na = 0, nb = 0;
#pragma unroll
            for (int m = 0; m < 5; ++m) {
                na += __popcll(__ballot(uA[m] >= cA));
                nb += __popcll(__ballot(uB[m] >= cB));
            }
            if (na >= K1SEL) preA = cA;
            if (nb >= K1SEL) preB = cB;
        }
        int gA = 0, gB = 0, eA = 0, eB = 0;
        uint32_t pA16 = preA >> 16, pB16 = preB >> 16;
#pragma unroll
        for (int m = 0; m < 5; ++m) {
            gA += __popcll(__ballot((uA[m] >> 16) >  pA16));
            eA += __popcll(__ballot((uA[m] >> 16) == pA16));
            gB += __popcll(__ballot((uB[m] >> 16) >  pB16));
            eB += __popcll(__ballot((uB[m] >> 16) == pB16));
        }
        uint32_t maskA = 0xFFFF0000u, maskB = 0xFFFF0000u;
        if ((K1SEL - gA < eA) || (K1SEL - gB < eB)) {
#pragma unroll 1
            for (int bit = 15; bit >= 0; --bit) {
                uint32_t cA = preA | (1u << bit);
                uint32_t cB = preB | (1u << bit);
                int na = 0, nb = 0;
#pragma unroll
                for (int m = 0; m < 5; ++m) {
                    na += __popcll(__ballot(uA[m] >= cA));
                    nb += __popcll(__ballot(uB[m] >= cB));
                }
                if (na >= K1SEL) preA = cA;
                if (nb >= K1SEL) preB = cB;
            }
            maskA = maskB = 0xFFFFFFFFu;
        }
        int cgtA = 0, cgtB = 0;
#pragma unroll
        for (int m = 0; m < 5; ++m) {
            cgtA += __popcll(__ballot((uA[m] & maskA) > preA));
            cgtB += __popcll(__ballot((uB[m] & maskB) > preB));
        }
        const int needA = K1SEL - cgtA;
        const int needB = K1SEL - cgtB;
        float* dstA = p1w + chp * 140 + 4;
        float* dstB = p1w + (chp + 1) * 140 + 4;
        int eqA = 0, kpA = 0, eqB = 0, kpB = 0;
#pragma unroll
        for (int m = 0; m < 5; ++m) {
            unsigned long long emA = __ballot((uA[m] & maskA) == preA);
            unsigned long long emB = __ballot((uB[m] & maskB) == preB);
            int erA = eqA + lane_prefix(emA);
            int erB = eqB + lane_prefix(emB);
            bool keepA = ((uA[m] & maskA) > preA) || (((uA[m] & maskA) == preA) && (erA < needA));
            bool keepB = ((uB[m] & maskB) > preB) || (((uB[m] & maskB) == preB) && (erB < needB));
            unsigned long long kmA = __ballot(keepA);
            unsigned long long kmB = __ballot(keepB);
            int posA = kpA + lane_prefix(kmA);
            int posB = kpB + lane_prefix(kmB);
            if (keepA) dstA[posA] = fast_tanh(acc[chp][m]);
            if (keepB) dstB[posB] = fast_tanh(acc[chp + 1][m]);
            eqA += __popcll(emA); kpA += __popcll(kmA);
            eqB += __popcll(emB); kpB += __popcll(kmB);
        }
    }

    // ---- conv2 partial: group g = 2sl+rs over its own 8 input channels ----
    float a2[16][3];
#pragma unroll
    for (int f2 = 0; f2 < 16; ++f2) {
        float bz = rs ? 0.f : b2c[sl * 16 + f2];   // pre-folded bias counted once
        a2[f2][0] = bz; a2[f2][1] = bz; a2[f2][2] = bz;
    }
    int tB[3];
#pragma unroll
    for (int tm = 0; tm < 3; ++tm) { int t = lane + 64 * tm; tB[tm] = (t < OUT2) ? t : (OUT2 - 1); }

    const int g = 2 * sl + rs;
#pragma unroll 1
    for (int ic = 0; ic < 8; ++ic) {
        const float* src = p1w + ic * 140;   // logical t' = idx - 4
#pragma unroll
        for (int k = 0; k < 5; ++k) {
            float v0 = src[tB[0] + k];
            float v1 = src[tB[1] + k];
            float v2 = src[tB[2] + k];
            const float* wp = &w2t[((g * 8 + ic) * 5 + k) * 16];
#pragma unroll
            for (int f2 = 0; f2 < 16; ++f2) {
                float w = wp[f2];
                a2[f2][0] = fmaf(w, v0, a2[f2][0]);
                a2[f2][1] = fmaf(w, v1, a2[f2][1]);
                a2[f2][2] = fmaf(w, v2, a2[f2][2]);
            }
        }
    }

    // ---- cross-wave fold (a2 sum) + top-4, in the pair's dead p1 regions ----
    float* scr = uni + (wv & ~1) * WREG;     // 2240 floats >= 16*137
    __syncthreads();                          // both halves' conv2 done
    if (rs) {
#pragma unroll
        for (int f2 = 0; f2 < 16; ++f2) {
            scr[f2 * 137 + lane]      = a2[f2][0];
            scr[f2 * 137 + lane + 64] = a2[f2][1];
            if (lane + 128 < OUT2) scr[f2 * 137 + lane + 128] = a2[f2][2];
        }
    }
    __syncthreads();
    if (!rs) {
#pragma unroll
        for (int f2 = 0; f2 < 16; ++f2) {
            scr[f2 * 137 + lane]      += a2[f2][0];
            scr[f2 * 137 + lane + 64] += a2[f2][1];
            if (lane + 128 < OUT2) scr[f2 * 137 + lane + 128] += a2[f2][2];
        }
        // top-4 (value desc, tie -> lower t): 4 lanes per f2, sorted top-4 merge
        const int f2o = lane >> 2, qq = lane & 3;
        const float* src = scr + f2o * 137 + qq * 34;
        const int tend = (qq == 3) ? (OUT2 - 102) : 34;   // 34,34,34,33
        const uint32_t tbase = 0xFFFFFFFFu - (uint32_t)(qq * 34);
        u64 L0 = 0, L1 = 0, L2 = 0, L3 = 0;
#pragma unroll 2
        for (int i = 0; i < 34; ++i) {
            float v = src[(i < tend) ? i : 0];
            u64 kk = ((u64)f2ord(v) << 32) | (u64)(tbase - (uint32_t)i);
            if (i >= tend) kk = 0;
            bool b0 = kk > L0, b1 = kk > L1, b2 = kk > L2, b3 = kk > L3;
            L3 = b3 ? (b2 ? L2 : kk) : L3;
            L2 = b2 ? (b1 ? L1 : kk) : L2;
            L1 = b1 ? (b0 ? L0 : kk) : L1;
            L0 = b0 ? kk : L0;
        }
#pragma unroll
        for (int d = 1; d <= 2; d <<= 1) {
            u64 M0 = shflx64(L0, d), M1 = shflx64(L1, d);
            u64 M2 = shflx64(L2, d), M3 = shflx64(L3, d);
            u64 r0 = maxu64(L0, M0);
            u64 r1 = minu64(maxu64(L0, M1), maxu64(L1, M0));
            u64 r2 = minu64(minu64(maxu64(L0, M2), maxu64(L1, M1)), maxu64(L2, M0));
            u64 r3k = minu64(minu64(maxu64(L0, M3), maxu64(L1, M2)),
                             minu64(maxu64(L2, M1), maxu64(L3, M0)));
            L0 = r0; L1 = r1; L2 = r2; L3 = r3k;
        }
        if (qq == 0) {
            // reorder by t ascending == low-32 word descending; emit raw (tanh in FC)
#define CSW2(a, bb) { if ((uint32_t)(bb) > (uint32_t)(a)) { u64 tt = (a); (a) = (bb); (bb) = tt; } }
            CSW2(L0, L1); CSW2(L2, L3); CSW2(L0, L2); CSW2(L1, L3); CSW2(L1, L2);
#undef CSW2
            float* qp = &p2loc[(wv >> 1) * 64 + f2o * 4];
            qp[0] = ord2f((uint32_t)(L0 >> 32));
            qp[1] = ord2f((uint32_t)(L1 >> 32));
            qp[2] = ord2f((uint32_t)(L2 >> 32));
            qp[3] = ord2f((uint32_t)(L3 >> 32));
        }
    }
    __syncthreads();

    // ---- FC partial over this block's 256 features (waves 0-3) ----
    if (wv < 4) {
        float pv = fast_tanh(p2loc[tid]);
        float part[6];
#pragma unroll
        for (int n = 0; n < 6; ++n) part[n] = pv * fcw[n * 1024 + q4 * 256 + tid];
#pragma unroll
        for (int n = 0; n < 6; ++n) {
            float s = part[n];
#pragma unroll
            for (int off = 32; off > 0; off >>= 1) s += __shfl_xor(s, off, 64);
            if (lane == 0) fred[wv][n] = s;
        }
    }
    __syncthreads();
    if (tid < 6)
        ws[FCP_OFF + blockIdx.x * 6 + tid] =
            fred[0][tid] + fred[1][tid] + fred[2][tid] + fred[3][tid];
}

// ------------- deterministic FC reduce: 4 block-partials per sample + bias -------------
extern "C" __global__ void dcnn_fcred(const float* __restrict__ ws, const float* __restrict__ fcb,
                                      float* __restrict__ out) {
    int i = blockIdx.x * 256 + threadIdx.x;   // 12*256 = 3072 = 512*6
    if (i >= 512 * 6) return;
    int s = i / 6, n = i - s * 6;
    const float* p = ws + FCP_OFF + s * 24 + n;
    out[i] = fcb[n] + ((p[0] + p[6]) + (p[12] + p[18]));
}

extern "C" void kernel_launch(void* const* d_in, const int* in_sizes, int n_in,
                              void* d_out, int out_size, void* d_ws, size_t ws_size,
                              hipStream_t stream) {
    (void)in_sizes; (void)n_in; (void)out_size; (void)ws_size;
    const int*   x   = (const int*)d_in[0];
    const float* emb = (const float*)d_in[1];
    const float* w1  = (const float*)d_in[2];
    const float* b1  = (const float*)d_in[3];
    const float* w2  = (const float*)d_in[4];
    const float* b2  = (const float*)d_in[5];
    const float* fcw = (const float*)d_in[6];
    const float* fcb = (const float*)d_in[7];
    float* outp = (float*)d_out;
    float* wsf  = (float*)d_ws;   // weights (24576 f) + FC partials (12288 f) ~ 148 KB

    dcnn_prep<<<96, 256, 0, stream>>>(w1, b1, w2, b2, wsf);
    dcnn_main<<<2048, 512, 0, stream>>>(x, emb, fcw, wsf);
    dcnn_fcred<<<12, 256, 0, stream>>>(wsf, fcb, outp);
}